// Round 7
// baseline (75.490 us; speedup 1.0000x reference)
//
#include <hip/hip_runtime.h>

#define D 64
#define EPSV 1e-9f

typedef __attribute__((ext_vector_type(8))) short bf8_t;   // 8 x bf16
typedef __attribute__((ext_vector_type(4))) float f4_t;

__device__ inline float bf2f(short u) {
    union { unsigned int i; float f; } v;
    v.i = ((unsigned int)(unsigned short)u) << 16;
    return v.f;
}
__device__ inline unsigned short f2bf(float f) {  // round-nearest-even
    union { float f; unsigned int i; } v; v.f = f;
    unsigned int r = v.i + 0x7fff + ((v.i >> 16) & 1);
    return (unsigned short)(r >> 16);
}

// --- Fused prep: cvt (blocks [0,cvtb)), wpack (next 32), row offsets (rest) ---
__global__ void prep_kernel(const float* __restrict__ node_feats,
                            const int*   __restrict__ edge_dst,
                            const float* __restrict__ W0,
                            const float* __restrict__ W1,
                            int* __restrict__ row_off,
                            unsigned short* __restrict__ Wpack,
                            unsigned short* __restrict__ X,   // [n][64] bf16
                            int n_nodes, int n_edges, int cvtb)
{
    const int bid = blockIdx.x;
    const int tid = threadIdx.x;
    if (bid < cvtb) {
        const int i = bid * 256 + tid;           // one per 4 floats
        if (i < n_nodes * 16) {
            const float4 v = ((const float4*)node_feats)[i];
            const int row = i >> 4, c4 = (i & 15) * 4;
            unsigned short* p = X + row * 64 + c4;
            p[0] = f2bf(v.x); p[1] = f2bf(v.y); p[2] = f2bf(v.z); p[3] = f2bf(v.w);
        }
    } else if (bid < cvtb + 32) {
        // Wpack[((t*4+kk)*64+lane)*8+j] = W[k][col], k=kk*32+(lane>>4)*8+j, col=t*16+(lane&15)
        const int idx = (bid - cvtb) * 256 + tid;
        const int j = idx & 7, lane = (idx >> 3) & 63, kk = (idx >> 9) & 3, t = idx >> 11;
        const int k = kk * 32 + (lane >> 4) * 8 + j;
        const int d = t * 16 + (lane & 15);
        const float v = (k < D) ? W0[d * D + k] : W1[d * D + (k - D)];
        Wpack[idx] = f2bf(v);
    } else {
        const int n = (bid - cvtb - 32) * 256 + tid;
        if (n <= n_nodes) {
            int lo = 0, hi = n_edges;
            while (lo < hi) {
                const int mid = (lo + hi) >> 1;
                if (edge_dst[mid] < n) lo = mid + 1; else hi = mid;
            }
            row_off[n] = lo;
        }
    }
}

// --- Fused layer: one block = one 16-row tile.
// Phase A: wave w aggregates nodes rowbase+w*4+{0..3} (8 gathers in flight),
//          writes bf16 msg into padded LDS tile.
// Phase B: wave w computes output cols [w*16, w*16+16) via 4 MFMA.
template<int OUT_F32>
__global__ __launch_bounds__(256, 4) void layer_kernel(
    const unsigned short* __restrict__ Xin,     // [n][64] bf16
    const int*   __restrict__ row_off,
    const int*   __restrict__ edge_src,
    const float* __restrict__ edge_w,
    const unsigned short* __restrict__ Wpack,   // fragment-packed, 8192 bf16
    const float* __restrict__ b0,
    const float* __restrict__ b1,
    void* __restrict__ outp,
    int n_nodes)
{
    // [16][72]: +16B row pad -> A-frag ds_read_b128 is 2-way max (free)
    __shared__ __align__(16) unsigned short lds_msg[16][72];

    const int lane = threadIdx.x & 63;
    const int w    = threadIdx.x >> 6;          // wave 0..3
    const int rowbase = blockIdx.x * 16;

    // ---------- Phase A: aggregate 4 nodes ----------
    const int nb = rowbase + w * 4;
    int s[4], e[4];
    #pragma unroll
    for (int i = 0; i < 4; ++i) {
        int n = nb + i; if (n >= n_nodes) n = n_nodes - 1;
        s[i] = row_off[n]; e[i] = row_off[n + 1];
    }
    int dmax = 0;
    #pragma unroll
    for (int i = 0; i < 4; ++i) { const int d = e[i] - s[i]; if (d > dmax) dmax = d; }

    const int slot = lane >> 3;        // 0..7
    const int fo   = (lane & 7) * 8;   // bf16 elem offset (16B chunk)

    float acc[4][8];
    float ws[4];
    #pragma unroll
    for (int i = 0; i < 4; ++i) {
        ws[i] = 0.f;
        #pragma unroll
        for (int m = 0; m < 8; ++m) acc[i][m] = 0.f;
    }

    for (int base = 0; base < dmax; base += 16) {
        #pragma unroll
        for (int i = 0; i < 4; ++i) {
            const int  ej0 = s[i] + base + slot;
            const int  ej1 = ej0 + 8;
            const bool v0 = ej0 < e[i], v1 = ej1 < e[i];
            const float w0 = v0 ? edge_w[ej0] : 0.f;
            const float w1 = v1 ? edge_w[ej1] : 0.f;
            const int  sc0 = v0 ? edge_src[ej0] : 0;
            const int  sc1 = v1 ? edge_src[ej1] : 0;
            const bf8_t f0 = *(const bf8_t*)(Xin + sc0 * 64 + fo);
            const bf8_t f1 = *(const bf8_t*)(Xin + sc1 * 64 + fo);
            #pragma unroll
            for (int m = 0; m < 8; ++m)
                acc[i][m] = fmaf(w0, bf2f(f0[m]), fmaf(w1, bf2f(f1[m]), acc[i][m]));
            ws[i] += w0 + w1;
        }
    }

    // butterfly over slot bits (lane bits 3,4,5): all lanes get full totals
    #pragma unroll
    for (int off = 8; off <= 32; off <<= 1) {
        #pragma unroll
        for (int i = 0; i < 4; ++i) {
            #pragma unroll
            for (int m = 0; m < 8; ++m) acc[i][m] += __shfl_xor(acc[i][m], off);
            ws[i] += __shfl_xor(ws[i], off);
        }
    }

    // lane-group g (0..3) writes node g's msg chunk (static acc index via unroll)
    const int g = lane >> 3;
    #pragma unroll
    for (int i = 0; i < 4; ++i) {
        if (g == i) {
            const float inv = 1.0f / (ws[i] + EPSV);
            bf8_t mv;
            #pragma unroll
            for (int m = 0; m < 8; ++m) mv[m] = (short)f2bf(acc[i][m] * inv);
            *(bf8_t*)(&lds_msg[w * 4 + i][fo]) = mv;
        }
    }

    __syncthreads();

    // ---------- Phase B: MFMA, wave w owns cols w*16 .. w*16+15 ----------
    bf8_t bfr[4];
    #pragma unroll
    for (int kk = 0; kk < 4; ++kk)
        bfr[kk] = *(const bf8_t*)(Wpack + ((w * 4 + kk) * 64 + lane) * 8);

    const int arow16 = lane & 15;
    const int koff   = (lane >> 4) * 8;
    int arow = rowbase + arow16; if (arow >= n_nodes) arow = n_nodes - 1;
    const unsigned short* ap = Xin + arow * 64 + koff;

    bf8_t af[4];
    af[0] = *(const bf8_t*)(ap);                          // k = koff + 0..7
    af[1] = *(const bf8_t*)(ap + 32);                     // k = 32 + koff ..
    af[2] = *(const bf8_t*)(&lds_msg[arow16][koff]);      // k = 64 + koff ..
    af[3] = *(const bf8_t*)(&lds_msg[arow16][koff + 32]); // k = 96 + koff ..

    f4_t acc4 = (f4_t){0.f, 0.f, 0.f, 0.f};
    #pragma unroll
    for (int kk = 0; kk < 4; ++kk)
        acc4 = __builtin_amdgcn_mfma_f32_16x16x32_bf16(af[kk], bfr[kk], acc4, 0, 0, 0);

    const int col  = w * 16 + (lane & 15);
    const float bias = b0[col] + b1[col];
    #pragma unroll
    for (int r = 0; r < 4; ++r) {
        const int row = rowbase + (lane >> 4) * 4 + r;
        if (row < n_nodes) {
            const float v = fmaxf(acc4[r] + bias, 0.0f);
            if (OUT_F32) ((float*)outp)[row * 64 + col] = v;
            else ((unsigned short*)outp)[row * 64 + col] = f2bf(v);
        }
    }
}

extern "C" void kernel_launch(void* const* d_in, const int* in_sizes, int n_in,
                              void* d_out, int out_size, void* d_ws, size_t ws_size,
                              hipStream_t stream) {
    const float* node_feats = (const float*)d_in[0];
    const int*   edge_src   = (const int*)  d_in[1];
    const int*   edge_dst   = (const int*)  d_in[2];
    const float* edge_w     = (const float*)d_in[3];
    const float* W0         = (const float*)d_in[4];
    const float* b0         = (const float*)d_in[5];
    const float* W1         = (const float*)d_in[6];
    const float* b1         = (const float*)d_in[7];

    const int n_nodes = in_sizes[0] / D;   // 50000
    const int n_edges = in_sizes[1];       // 800000

    // workspace layout (256B-aligned)
    char* ws = (char*)d_ws;
    int*            row_off = (int*)ws;                         // (n+1) ints
    unsigned short* Wpack   = (unsigned short*)(ws + 204800);   // 16384 B
    unsigned short* X0      = (unsigned short*)(ws + 237568);   // n*64*2 = 6.4 MB
    unsigned short* X1      = (unsigned short*)(ws + 237568 + 6400000); // 6.4 MB

    const int cvtb = (n_nodes * 16 + 255) / 256;    // 3125
    const int offb = (n_nodes + 1 + 255) / 256;     // 196
    prep_kernel<<<cvtb + 32 + offb, 256, 0, stream>>>(node_feats, edge_dst, W0, W1,
                                                      row_off, Wpack, X0,
                                                      n_nodes, n_edges, cvtb);

    const int ntiles = (n_nodes + 15) / 16;         // 3125

    layer_kernel<0><<<ntiles, 256, 0, stream>>>(X0, row_off, edge_src, edge_w,
                                                Wpack, b0, b1, X1, n_nodes);
    layer_kernel<1><<<ntiles, 256, 0, stream>>>(X1, row_off, edge_src, edge_w,
                                                Wpack, b0, b1, d_out, n_nodes);
}